// Round 3
// baseline (196.203 us; speedup 1.0000x reference)
//
#include <hip/hip_runtime.h>

constexpr int Bn = 64, Sn = 512, Hn = 768, Tn = 9;
constexpr int EMS = 12;                 // padded emission row stride (floats)
constexpr int CHUNKS = 16, CLEN = 32;   // CHUNKS*CLEN == Sn

__device__ __forceinline__ float lse9(const float* e) {
    float m01 = fmaxf(e[0], e[1]), m23 = fmaxf(e[2], e[3]);
    float m45 = fmaxf(e[4], e[5]), m67 = fmaxf(e[6], e[7]);
    float m = fmaxf(fmaxf(fmaxf(m01, m23), fmaxf(m45, m67)), e[8]);
    float s = 0.f;
#pragma unroll
    for (int k = 0; k < 9; ++k) s += __expf(e[k] - m);
    return m + __logf(s);
}

// ---------------- K1: emissions = hidden @ W + b ----------------
// one wave per (b,s) row; float4 coalesced hidden loads; W in registers.
__global__ __launch_bounds__(256) void emis_kernel(
        const float* __restrict__ hidden, const float* __restrict__ W,
        const float* __restrict__ bias, float* __restrict__ em,
        int nrows, int nwaves) {
    const int lane = threadIdx.x & 63;
    const int wid  = blockIdx.x * (blockDim.x >> 6) + (threadIdx.x >> 6);
    // register-cache W rows this lane needs: h = 4*lane + 256*k + c
    float wr[3][4][9];
#pragma unroll
    for (int k = 0; k < 3; ++k)
#pragma unroll
        for (int c = 0; c < 4; ++c) {
            const int h = 4 * lane + 256 * k + c;
#pragma unroll
            for (int t = 0; t < 9; ++t) wr[k][c][t] = W[h * 9 + t];
        }
    for (int row = wid; row < nrows; row += nwaves) {
        const float4* hp = reinterpret_cast<const float4*>(hidden + (size_t)row * Hn);
        float4 v0 = hp[lane], v1 = hp[lane + 64], v2 = hp[lane + 128];
        const float hv[3][4] = {{v0.x, v0.y, v0.z, v0.w},
                                {v1.x, v1.y, v1.z, v1.w},
                                {v2.x, v2.y, v2.z, v2.w}};
        float acc[9];
#pragma unroll
        for (int t = 0; t < 9; ++t) acc[t] = 0.f;
#pragma unroll
        for (int k = 0; k < 3; ++k)
#pragma unroll
            for (int c = 0; c < 4; ++c)
#pragma unroll
                for (int t = 0; t < 9; ++t)
                    acc[t] = fmaf(hv[k][c], wr[k][c][t], acc[t]);
        // full-wave butterfly reduction of the 9 partial dots
#pragma unroll
        for (int m = 1; m < 64; m <<= 1)
#pragma unroll
            for (int t = 0; t < 9; ++t) acc[t] += __shfl_xor(acc[t], m, 64);
        if (lane == 0) {
            float* o = em + (size_t)row * EMS;
#pragma unroll
            for (int t = 0; t < 9; ++t) o[t] = acc[t] + bias[t];
        }
    }
}

// ---------------- K2: per-(batch,chunk) 9x9 log-matrix ----------------
// thread (i,j) runs row-i unit-vector recursion, computes column j element.
__global__ __launch_bounds__(128) void chunk_kernel(
        const float* __restrict__ em, const float* __restrict__ trans,
        const int* __restrict__ labels, float* __restrict__ Mws) {
    const int b = blockIdx.x / CHUNKS;
    const int c = blockIdx.x % CHUNKS;
    const int tid = threadIdx.x;
    const bool act = tid < 81;
    const int i = tid / 9, j = tid % 9;
    __shared__ float Mbuf[2][9][12];     // double-buffered state matrix
    __shared__ float emch[CLEN][EMS];    // prefetched emissions for chunk
    __shared__ int   labch[CLEN];
    const int s0 = c * CLEN;
    const float* emb = em + ((size_t)b * Sn + s0) * EMS;
    for (int idx = tid; idx < CLEN * EMS; idx += 128)
        (&emch[0][0])[idx] = emb[idx];
    if (tid < CLEN) labch[tid] = labels[b * Sn + s0 + tid];
    float tc[9], row[9];
    float nv = (i == j) ? 0.f : -1e30f;  // my own M[i][j], starts as log-identity
    if (act) {
#pragma unroll
        for (int k = 0; k < 9; ++k) tc[k] = trans[k * 9 + j];  // column j of trans
#pragma unroll
        for (int k = 0; k < 9; ++k) row[k] = (k == i) ? 0.f : -1e30f;
    }
    __syncthreads();
    const int sbeg = (c == 0) ? 1 : 0;   // global steps are s=1..511
    for (int sl = sbeg; sl < CLEN; ++sl) {
        if (act) {
            float e[9];
#pragma unroll
            for (int k = 0; k < 9; ++k) e[k] = row[k] + tc[k];
            float cand = lse9(e) + emch[sl][j];
            if (labch[sl] > -1) nv = cand;     // mask: keep old value if invalid
            Mbuf[sl & 1][i][j] = nv;
        }
        __syncthreads();
        if (act) {
#pragma unroll
            for (int k = 0; k < 9; ++k) row[k] = Mbuf[sl & 1][i][k];
        }
    }
    if (act) Mws[(size_t)(b * CHUNKS + c) * 81 + tid] = nv;
}

// ---------------- K3: fold chunks + numerator + output ----------------
__global__ __launch_bounds__(128) void final_kernel(
        const float* __restrict__ em, const float* __restrict__ Mws,
        const float* __restrict__ start, const float* __restrict__ endt,
        const float* __restrict__ trans, const int* __restrict__ labels,
        float* __restrict__ out) {
    const int b = blockIdx.x, tid = threadIdx.x;
    __shared__ float Ml[CHUNKS][9][12];
    __shared__ float red[128];
    for (int idx = tid; idx < CHUNKS * 81; idx += 128) {
        int c = idx / 81, r = idx % 81;
        Ml[c][r / 9][r % 9] = Mws[(size_t)(b * CHUNKS + c) * 81 + r];
    }
    // numerator partial sums (mask==all-valid for given inputs; prev=tags[s-1])
    const int* lb = labels + b * Sn;
    float np = 0.f;
    for (int s = tid; s < Sn; s += 128) {
        if (s >= 1) {
            int l = lb[s];
            if (l > -1) {
                int tp = lb[s - 1]; tp = tp > -1 ? tp : 0;
                np += trans[tp * 9 + l] + em[((size_t)b * Sn + s) * EMS + l];
            }
        }
    }
    red[tid] = np;
    __syncthreads();
    for (int off = 64; off > 0; off >>= 1) {
        if (tid < off) red[tid] += red[tid + off];
        __syncthreads();
    }
    if (tid < 9) {
        const int j = tid;
        float alpha[9];
#pragma unroll
        for (int k = 0; k < 9; ++k)
            alpha[k] = start[k] + em[(size_t)b * Sn * EMS + k];
        for (int c = 0; c < CHUNKS; ++c) {
            float e[9];
#pragma unroll
            for (int k = 0; k < 9; ++k) e[k] = alpha[k] + Ml[c][k][j];
            float nv = lse9(e);
#pragma unroll
            for (int k = 0; k < 9; ++k) alpha[k] = __shfl(nv, k, 64);
        }
        if (j == 0) {
            float e[9];
#pragma unroll
            for (int k = 0; k < 9; ++k) e[k] = alpha[k] + endt[k];
            float den = lse9(e);
            int t0 = lb[0] > -1 ? lb[0] : 0;
            float num = red[0] + start[t0] + em[(size_t)b * Sn * EMS + t0];
            int lt = lb[Sn - 1] > -1 ? lb[Sn - 1] : 0;
            num += endt[lt];
            atomicAdd(out, (den - num) * (1.0f / Bn));
        }
    }
}

extern "C" void kernel_launch(void* const* d_in, const int* in_sizes, int n_in,
                              void* d_out, int out_size, void* d_ws, size_t ws_size,
                              hipStream_t stream) {
    const float* hidden = (const float*)d_in[0];
    const float* W      = (const float*)d_in[1];
    const float* bias   = (const float*)d_in[2];
    const float* start  = (const float*)d_in[3];
    const float* endt   = (const float*)d_in[4];
    const float* trans  = (const float*)d_in[5];
    const int*   labels = (const int*)d_in[6];
    float* out = (float*)d_out;

    float* em  = (float*)d_ws;                       // 32768*12 f32 = 1.5 MB
    float* Mws = em + (size_t)Bn * Sn * EMS;         // 64*16*81 f32 = 324 KB

    hipMemsetAsync(d_out, 0, sizeof(float), stream);

    const int nrows  = Bn * Sn;            // 32768
    const int blocks = 1024;               // 4096 waves -> 8 rows/wave
    emis_kernel<<<blocks, 256, 0, stream>>>(hidden, W, bias, em, nrows, blocks * 4);
    chunk_kernel<<<Bn * CHUNKS, 128, 0, stream>>>(em, trans, labels, Mws);
    final_kernel<<<Bn, 128, 0, stream>>>(em, Mws, start, endt, trans, labels, out);
}

// Round 4
// 195.222 us; speedup vs baseline: 1.0050x; 1.0050x over previous
//
#include <hip/hip_runtime.h>

constexpr int Bn = 64, Sn = 512, Hn = 768, Tn = 9;
constexpr int EMS = 12;                  // padded row stride (floats)
constexpr int CHUNKS = 32, CLEN = 16;    // CHUNKS*CLEN == Sn

__device__ __forceinline__ float lse9(const float* e) {
    float m01 = fmaxf(e[0], e[1]), m23 = fmaxf(e[2], e[3]);
    float m45 = fmaxf(e[4], e[5]), m67 = fmaxf(e[6], e[7]);
    float m = fmaxf(fmaxf(fmaxf(m01, m23), fmaxf(m45, m67)), e[8]);
    float s = 0.f;
#pragma unroll
    for (int k = 0; k < 9; ++k) s += __expf(e[k] - m);
    return m + __logf(s);
}

// ---- fused: emissions for one (b,chunk) + chunk 9x9 log-matrix + numerator ----
// block = 128 threads (2 waves). Phase A: wave-per-row emissions (8 rows/wave),
// W staged via LDS (coalesced) then register-cached per lane.
// Phase B: threads (i,j)<81 run the 9x9 log-semiring recursion over CLEN steps.
__global__ __launch_bounds__(128) void fused_kernel(
        const float* __restrict__ hidden, const float* __restrict__ W,
        const float* __restrict__ bias, const float* __restrict__ trans,
        const int* __restrict__ labels,
        float* __restrict__ Mws, float* __restrict__ numpart,
        float* __restrict__ em0) {
    __shared__ float Wl[Hn * Tn];          // 27648 B
    __shared__ float emch[CLEN][EMS];      // chunk emissions
    __shared__ float Mbuf[2][9][12];       // double-buffered state matrix
    __shared__ int   labch[CLEN];

    const int b = blockIdx.x / CHUNKS;
    const int c = blockIdx.x % CHUNKS;
    const int tid = threadIdx.x;
    const int lane = tid & 63;
    const int wv = tid >> 6;               // 0..1

    // ---- stage W into LDS, coalesced ----
    const float4* Wg4 = reinterpret_cast<const float4*>(W);
    float4* Wl4 = reinterpret_cast<float4*>(Wl);
    for (int idx = tid; idx < Hn * Tn / 4; idx += 128) Wl4[idx] = Wg4[idx];
    if (tid < CLEN) labch[tid] = labels[b * Sn + c * CLEN + tid];
    float br[9];
#pragma unroll
    for (int t = 0; t < 9; ++t) br[t] = bias[t];
    __syncthreads();

    // ---- phase A: emissions. issue first row's global loads BEFORE W ds_reads
    const size_t hbase = ((size_t)b * Sn + (size_t)c * CLEN) * Hn;
    const float4* hp0 = reinterpret_cast<const float4*>(hidden + hbase + (size_t)wv * Hn);
    float4 pre0 = hp0[lane], pre1 = hp0[lane + 64], pre2 = hp0[lane + 128];

    // per-lane W register cache from LDS: rows h = 4*lane + 256*k + cc
    float wreg[3][36];
#pragma unroll
    for (int k = 0; k < 3; ++k) {
        const float4* p = reinterpret_cast<const float4*>(&Wl[(4 * lane + 256 * k) * Tn]);
#pragma unroll
        for (int j = 0; j < 9; ++j) {
            float4 q = p[j];
            wreg[k][4 * j + 0] = q.x; wreg[k][4 * j + 1] = q.y;
            wreg[k][4 * j + 2] = q.z; wreg[k][4 * j + 3] = q.w;
        }
    }

    for (int r = wv; r < CLEN; r += 2) {
        float4 v0 = pre0, v1 = pre1, v2 = pre2;
        if (r + 2 < CLEN) {
            const float4* hq = reinterpret_cast<const float4*>(hidden + hbase + (size_t)(r + 2) * Hn);
            pre0 = hq[lane]; pre1 = hq[lane + 64]; pre2 = hq[lane + 128];
        }
        const float hv[12] = {v0.x, v0.y, v0.z, v0.w, v1.x, v1.y, v1.z, v1.w,
                              v2.x, v2.y, v2.z, v2.w};
        float acc[9];
#pragma unroll
        for (int t = 0; t < 9; ++t) acc[t] = 0.f;
#pragma unroll
        for (int k = 0; k < 3; ++k)
#pragma unroll
            for (int cc = 0; cc < 4; ++cc)
#pragma unroll
                for (int t = 0; t < 9; ++t)
                    acc[t] = fmaf(hv[k * 4 + cc], wreg[k][cc * 9 + t], acc[t]);
#pragma unroll
        for (int m = 1; m < 64; m <<= 1)
#pragma unroll
            for (int t = 0; t < 9; ++t) acc[t] += __shfl_xor(acc[t], m, 64);
        if (lane == 0) {
#pragma unroll
            for (int t = 0; t < 9; ++t) emch[r][t] = acc[t] + br[t];
        }
    }
    __syncthreads();

    // ---- numerator partial for this chunk (wave 0) ----
    if (tid < 64) {
        float term = 0.f;
        if (tid < CLEN) {
            int sg = c * CLEN + tid;
            if (sg >= 1) {
                int l = labch[tid];
                if (l > -1) {
                    int lp = (tid > 0) ? labch[tid - 1] : labels[b * Sn + sg - 1];
                    if (lp < 0) lp = 0;
                    term = trans[lp * 9 + l] + emch[tid][l];
                }
            }
        }
#pragma unroll
        for (int m = 1; m < 16; m <<= 1) term += __shfl_xor(term, m, 64);
        if (tid == 0) numpart[b * CHUNKS + c] = term;
        if (c == 0 && tid < 9) em0[b * EMS + tid] = emch[0][tid];
    }

    // ---- phase B: 9x9 log-semiring chunk matrix ----
    const bool act = tid < 81;
    const int i = tid / 9, j = tid % 9;
    float tc[9], row[9];
    float nv = (i == j) ? 0.f : -1e30f;
    if (act) {
#pragma unroll
        for (int k = 0; k < 9; ++k) tc[k] = trans[k * 9 + j];
#pragma unroll
        for (int k = 0; k < 9; ++k) row[k] = (k == i) ? 0.f : -1e30f;
    }
    const int sbeg = (c == 0) ? 1 : 0;
    for (int sl = sbeg; sl < CLEN; ++sl) {
        if (act) {
            float e[9];
#pragma unroll
            for (int k = 0; k < 9; ++k) e[k] = row[k] + tc[k];
            float cand = lse9(e) + emch[sl][j];
            if (labch[sl] > -1) nv = cand;
            Mbuf[sl & 1][i][j] = nv;
        }
        __syncthreads();
        if (act) {
#pragma unroll
            for (int k = 0; k < 9; ++k) row[k] = Mbuf[sl & 1][i][k];
        }
    }
    if (act) Mws[(size_t)(b * CHUNKS + c) * 81 + tid] = nv;
}

// ---- final: fold 32 chunk matrices per batch + assemble loss ----
__global__ __launch_bounds__(128) void final_kernel(
        const float* __restrict__ Mws, const float* __restrict__ numpart,
        const float* __restrict__ em0, const float* __restrict__ start,
        const float* __restrict__ endt, const int* __restrict__ labels,
        float* __restrict__ out) {
    const int b = blockIdx.x, tid = threadIdx.x;
    __shared__ float Ml[CHUNKS][9][12];
    __shared__ float nred;
    for (int idx = tid; idx < CHUNKS * 81; idx += 128) {
        int c = idx / 81, r = idx % 81;
        Ml[c][r / 9][r % 9] = Mws[(size_t)(b * CHUNKS + c) * 81 + r];
    }
    if (tid < 64) {
        float np = (tid < CHUNKS) ? numpart[b * CHUNKS + tid] : 0.f;
#pragma unroll
        for (int m = 1; m < 32; m <<= 1) np += __shfl_xor(np, m, 64);
        if (tid == 0) nred = np;
    }
    __syncthreads();
    if (tid < 9) {
        const int j = tid;
        float alpha[9];
#pragma unroll
        for (int k = 0; k < 9; ++k) alpha[k] = start[k] + em0[b * EMS + k];
        for (int c = 0; c < CHUNKS; ++c) {
            float e[9];
#pragma unroll
            for (int k = 0; k < 9; ++k) e[k] = alpha[k] + Ml[c][k][j];
            float nv = lse9(e);
#pragma unroll
            for (int k = 0; k < 9; ++k) alpha[k] = __shfl(nv, k, 64);
        }
        if (j == 0) {
            float e[9];
#pragma unroll
            for (int k = 0; k < 9; ++k) e[k] = alpha[k] + endt[k];
            float den = lse9(e);
            const int* lb = labels + b * Sn;
            int t0 = lb[0] > -1 ? lb[0] : 0;
            int lt = lb[Sn - 1] > -1 ? lb[Sn - 1] : 0;
            float num = nred + start[t0] + em0[b * EMS + t0] + endt[lt];
            atomicAdd(out, (den - num) * (1.0f / Bn));
        }
    }
}

extern "C" void kernel_launch(void* const* d_in, const int* in_sizes, int n_in,
                              void* d_out, int out_size, void* d_ws, size_t ws_size,
                              hipStream_t stream) {
    const float* hidden = (const float*)d_in[0];
    const float* W      = (const float*)d_in[1];
    const float* bias   = (const float*)d_in[2];
    const float* start  = (const float*)d_in[3];
    const float* endt   = (const float*)d_in[4];
    const float* trans  = (const float*)d_in[5];
    const int*   labels = (const int*)d_in[6];
    float* out = (float*)d_out;

    float* numpart = (float*)d_ws;                    // 64*32
    float* em0     = numpart + Bn * CHUNKS;           // 64*12
    float* Mws     = em0 + Bn * EMS;                  // 64*32*81

    hipMemsetAsync(d_out, 0, sizeof(float), stream);
    fused_kernel<<<Bn * CHUNKS, 128, 0, stream>>>(hidden, W, bias, trans, labels,
                                                  Mws, numpart, em0);
    final_kernel<<<Bn, 128, 0, stream>>>(Mws, numpart, em0, start, endt, labels, out);
}